// Round 1
// baseline (402.086 us; speedup 1.0000x reference)
//
#include <hip/hip_runtime.h>

// SPH pressure-gradient: segmented scatter-reduce over E=8M edges, N=200k particles.
// i is SORTED -> per-thread run-length accumulation, atomicAdd only at segment flips.

constexpr int CHUNK = 16;   // edges per thread; E % CHUNK == 0 for this problem (8M/16)

__global__ void edge_kernel(const int*   __restrict__ ei,
                            const int*   __restrict__ ej,
                            const float* __restrict__ Vj,
                            const float2* __restrict__ dirs,
                            const float* __restrict__ qarr,
                            const float* __restrict__ support,
                            const float* __restrict__ p_i,
                            const float* __restrict__ p_j,
                            float*       __restrict__ acc,   // [N*2], pre-zeroed
                            int E)
{
    long long base = (long long)(blockIdx.x * (long long)blockDim.x + threadIdx.x) * CHUNK;
    if (base >= E) return;

    const float h    = support[0];
    const float coef = -20.0f * (7.0f / 3.14159265358979323846f) / (h * h * h);

    float ax = 0.0f, ay = 0.0f;
    int   cur = -1;

    #pragma unroll
    for (int k = 0; k < CHUNK; ++k) {
        long long e = base + k;
        if (e < E) {
            int    ii = ei[e];
            int    jj = ej[e];
            float  qq = qarr[e];
            float2 d  = dirs[e];
            float  om = 1.0f - qq;
            float  mag = coef * qq * om * om * om;
            float  w   = (p_i[ii] + p_j[jj]) * Vj[jj] * mag;
            if (ii != cur) {
                if (cur >= 0) {
                    atomicAdd(&acc[2 * cur],     ax);
                    atomicAdd(&acc[2 * cur + 1], ay);
                }
                cur = ii;
                ax = 0.0f;
                ay = 0.0f;
            }
            ax += w * d.x;
            ay += w * d.y;
        }
    }
    if (cur >= 0) {
        atomicAdd(&acc[2 * cur],     ax);
        atomicAdd(&acc[2 * cur + 1], ay);
    }
}

__global__ void finalize_kernel(float2* __restrict__ out,
                                const float* __restrict__ rhoi,
                                int N)
{
    int n = blockIdx.x * blockDim.x + threadIdx.x;
    if (n < N) {
        float2 a  = out[n];
        float  sc = -1.0f / rhoi[n];
        out[n] = make_float2(a.x * sc, a.y * sc);
    }
}

extern "C" void kernel_launch(void* const* d_in, const int* in_sizes, int n_in,
                              void* d_out, int out_size, void* d_ws, size_t ws_size,
                              hipStream_t stream)
{
    // setup_inputs order:
    // 0:i 1:j 2:ri 3:rj 4:Vi 5:Vj 6:distances 7:radialDistances
    // 8:support 9:numParticles 10:eps 11:rhoi 12:rhoj 13:pi 14:pj
    const int*    ei      = (const int*)   d_in[0];
    const int*    ej      = (const int*)   d_in[1];
    const float*  Vj      = (const float*) d_in[5];
    const float2* dirs    = (const float2*)d_in[6];
    const float*  qarr    = (const float*) d_in[7];
    const float*  support = (const float*) d_in[8];
    const float*  rhoi    = (const float*) d_in[11];
    const float*  p_i     = (const float*) d_in[13];
    const float*  p_j     = (const float*) d_in[14];

    const int E = in_sizes[0];
    const int N = in_sizes[11];

    float* out = (float*)d_out;

    // zero the accumulator (d_out doubles as accumulator; graph-capture-safe)
    hipMemsetAsync(out, 0, (size_t)N * 2 * sizeof(float), stream);

    const int nthreads = (E + CHUNK - 1) / CHUNK;
    const int block    = 256;
    const int grid     = (nthreads + block - 1) / block;
    edge_kernel<<<grid, block, 0, stream>>>(ei, ej, Vj, dirs, qarr, support,
                                            p_i, p_j, out, E);

    const int gridN = (N + block - 1) / block;
    finalize_kernel<<<gridN, block, 0, stream>>>((float2*)out, rhoi, N);
}

// Round 2
// 260.619 us; speedup vs baseline: 1.5428x; 1.5428x over previous
//
#include <hip/hip_runtime.h>

// SPH pressure-gradient: segmented scatter-reduce over E=8M edges, N=200k particles.
// i is SORTED. CHUNK=4 + vector loads => every edge-stream load instruction is
// fully coalesced (lane stride 16B). Per-thread run-length accumulation keeps
// atomics at ~1.1 flushes per 4 edges.

constexpr int CHUNK = 4;

__global__ __launch_bounds__(256) void edge_kernel(
    const int*   __restrict__ ei,
    const int*   __restrict__ ej,
    const float* __restrict__ Vj,
    const float* __restrict__ dirs,   // [E*2] interleaved x,y
    const float* __restrict__ qarr,
    const float* __restrict__ support,
    const float* __restrict__ p_i,
    const float* __restrict__ p_j,
    float*       __restrict__ acc,    // [N*2], pre-zeroed
    int E)
{
    long long t    = blockIdx.x * (long long)blockDim.x + threadIdx.x;
    long long base = t * CHUNK;
    if (base >= E) return;

    const float h    = support[0];
    const float coef = -20.0f * (7.0f / 3.14159265358979323846f) / (h * h * h);

    int   ii[CHUNK], jj[CHUNK];
    float qq[CHUNK], dxv[CHUNK], dyv[CHUNK];
    int   nk;

    if (base + CHUNK <= E) {
        // fully coalesced vector loads
        int4   i4  = *(const int4*)  (ei   + base);
        int4   j4  = *(const int4*)  (ej   + base);
        float4 q4  = *(const float4*)(qarr + base);
        float4 d01 = *(const float4*)(dirs + 2 * base);
        float4 d23 = *(const float4*)(dirs + 2 * base + 4);
        ii[0]=i4.x; ii[1]=i4.y; ii[2]=i4.z; ii[3]=i4.w;
        jj[0]=j4.x; jj[1]=j4.y; jj[2]=j4.z; jj[3]=j4.w;
        qq[0]=q4.x; qq[1]=q4.y; qq[2]=q4.z; qq[3]=q4.w;
        dxv[0]=d01.x; dyv[0]=d01.y; dxv[1]=d01.z; dyv[1]=d01.w;
        dxv[2]=d23.x; dyv[2]=d23.y; dxv[3]=d23.z; dyv[3]=d23.w;
        nk = CHUNK;
    } else {
        nk = (int)(E - base);
        for (int k = 0; k < nk; ++k) {
            ii[k]  = ei[base + k];
            jj[k]  = ej[base + k];
            qq[k]  = qarr[base + k];
            dxv[k] = dirs[2 * (base + k)];
            dyv[k] = dirs[2 * (base + k) + 1];
        }
    }

    float ax = 0.0f, ay = 0.0f;
    int   cur = ii[0];

    #pragma unroll
    for (int k = 0; k < CHUNK; ++k) {
        if (k < nk) {
            float om  = 1.0f - qq[k];
            float mag = coef * qq[k] * om * om * om;
            float w   = (p_i[ii[k]] + p_j[jj[k]]) * Vj[jj[k]] * mag;
            if (ii[k] != cur) {
                atomicAdd(&acc[2 * cur],     ax);
                atomicAdd(&acc[2 * cur + 1], ay);
                cur = ii[k];
                ax = 0.0f;
                ay = 0.0f;
            }
            ax += w * dxv[k];
            ay += w * dyv[k];
        }
    }
    atomicAdd(&acc[2 * cur],     ax);
    atomicAdd(&acc[2 * cur + 1], ay);
}

__global__ void finalize_kernel(float2* __restrict__ out,
                                const float* __restrict__ rhoi,
                                int N)
{
    int n = blockIdx.x * blockDim.x + threadIdx.x;
    if (n < N) {
        float2 a  = out[n];
        float  sc = -1.0f / rhoi[n];
        out[n] = make_float2(a.x * sc, a.y * sc);
    }
}

extern "C" void kernel_launch(void* const* d_in, const int* in_sizes, int n_in,
                              void* d_out, int out_size, void* d_ws, size_t ws_size,
                              hipStream_t stream)
{
    // setup_inputs order:
    // 0:i 1:j 2:ri 3:rj 4:Vi 5:Vj 6:distances 7:radialDistances
    // 8:support 9:numParticles 10:eps 11:rhoi 12:rhoj 13:pi 14:pj
    const int*   ei      = (const int*)  d_in[0];
    const int*   ej      = (const int*)  d_in[1];
    const float* Vj      = (const float*)d_in[5];
    const float* dirs    = (const float*)d_in[6];
    const float* qarr    = (const float*)d_in[7];
    const float* support = (const float*)d_in[8];
    const float* rhoi    = (const float*)d_in[11];
    const float* p_i     = (const float*)d_in[13];
    const float* p_j     = (const float*)d_in[14];

    const int E = in_sizes[0];
    const int N = in_sizes[11];

    float* out = (float*)d_out;

    hipMemsetAsync(out, 0, (size_t)N * 2 * sizeof(float), stream);

    const long long nthreads = ((long long)E + CHUNK - 1) / CHUNK;
    const int block = 256;
    const int grid  = (int)((nthreads + block - 1) / block);
    edge_kernel<<<grid, block, 0, stream>>>(ei, ej, Vj, dirs, qarr, support,
                                            p_i, p_j, out, E);

    const int gridN = (N + block - 1) / block;
    finalize_kernel<<<gridN, block, 0, stream>>>((float2*)out, rhoi, N);
}

// Round 3
// 67.111 us; speedup vs baseline: 5.9914x; 3.8834x over previous
//
#include <hip/hip_runtime.h>

// SPH pressure-gradient segmented scatter-reduce. i is SORTED.
// R3: wave-level segmented scan (shfl_up) -> ~7 atomic pairs per wave instead
// of ~140; packed {p,V} float2 gather halves scattered loads.

constexpr int CHUNK = 4;

__global__ void pack_pv(const float* __restrict__ p,
                        const float* __restrict__ V,
                        float2* __restrict__ pv, int N)
{
    int n = blockIdx.x * blockDim.x + threadIdx.x;
    if (n < N) pv[n] = make_float2(p[n], V[n]);
}

template <bool PACKED>
__global__ __launch_bounds__(256) void edge_kernel(
    const int*    __restrict__ ei,
    const int*    __restrict__ ej,
    const float*  __restrict__ Vj,
    const float*  __restrict__ dirs,   // [E*2] interleaved x,y
    const float*  __restrict__ qarr,
    const float*  __restrict__ support,
    const float*  __restrict__ p_i,
    const float*  __restrict__ p_j,
    const float2* __restrict__ pv,     // packed {p, V} (if PACKED)
    float*        __restrict__ acc,    // [N*2], pre-zeroed
    long long E)
{
    long long t    = blockIdx.x * (long long)blockDim.x + threadIdx.x;
    long long base = t * CHUNK;
    const int lane = threadIdx.x & 63;

    int   cur = -1;
    float ax = 0.0f, ay = 0.0f;

    if (base < E) {
        const float h    = support[0];
        const float coef = -20.0f * (7.0f / 3.14159265358979323846f) / (h * h * h);

        int   ii[CHUNK], jj[CHUNK];
        float qq[CHUNK], dxv[CHUNK], dyv[CHUNK];
        int   nk;

        if (base + CHUNK <= E) {
            int4   i4  = *(const int4*)  (ei   + base);
            int4   j4  = *(const int4*)  (ej   + base);
            float4 q4  = *(const float4*)(qarr + base);
            float4 d01 = *(const float4*)(dirs + 2 * base);
            float4 d23 = *(const float4*)(dirs + 2 * base + 4);
            ii[0]=i4.x; ii[1]=i4.y; ii[2]=i4.z; ii[3]=i4.w;
            jj[0]=j4.x; jj[1]=j4.y; jj[2]=j4.z; jj[3]=j4.w;
            qq[0]=q4.x; qq[1]=q4.y; qq[2]=q4.z; qq[3]=q4.w;
            dxv[0]=d01.x; dyv[0]=d01.y; dxv[1]=d01.z; dyv[1]=d01.w;
            dxv[2]=d23.x; dyv[2]=d23.y; dxv[3]=d23.z; dyv[3]=d23.w;
            nk = CHUNK;
        } else {
            nk = (int)(E - base);
            #pragma unroll
            for (int k = 0; k < CHUNK; ++k) {
                if (k < nk) {
                    ii[k]  = ei[base + k];
                    jj[k]  = ej[base + k];
                    qq[k]  = qarr[base + k];
                    dxv[k] = dirs[2 * (base + k)];
                    dyv[k] = dirs[2 * (base + k) + 1];
                } else { ii[k] = 0; jj[k] = 0; qq[k] = 0.0f; dxv[k] = 0.0f; dyv[k] = 0.0f; }
            }
        }

        // gather phase first: all scattered loads issued before use (ILP)
        float w[CHUNK];
        #pragma unroll
        for (int k = 0; k < CHUNK; ++k) {
            float pjv, vjv;
            if (PACKED) {
                float2 t2 = pv[jj[k]];
                pjv = t2.x; vjv = t2.y;
            } else {
                pjv = p_j[jj[k]];
                vjv = Vj[jj[k]];
            }
            float om = 1.0f - qq[k];
            w[k] = (p_i[ii[k]] + pjv) * vjv * (coef * qq[k] * om * om * om);
        }

        // per-thread run-length accumulate; interior flush on segment change
        cur = ii[0];
        #pragma unroll
        for (int k = 0; k < CHUNK; ++k) {
            if (k < nk) {
                if (ii[k] != cur) {
                    atomicAdd(&acc[2 * cur],     ax);
                    atomicAdd(&acc[2 * cur + 1], ay);
                    cur = ii[k];
                    ax = 0.0f; ay = 0.0f;
                }
                ax += w[k] * dxv[k];
                ay += w[k] * dyv[k];
            }
        }
    }

    // wave-level segmented inclusive scan over (cur, ax, ay); keys sorted.
    // All 64 lanes participate (inactive lanes carry cur=-1).
    #pragma unroll
    for (int d = 1; d < 64; d <<= 1) {
        int   oc  = __shfl_up(cur, d);
        float oax = __shfl_up(ax,  d);
        float oay = __shfl_up(ay,  d);
        if (lane >= d && oc == cur) { ax += oax; ay += oay; }
    }
    int nxt = __shfl_down(cur, 1);
    if (cur >= 0 && (lane == 63 || nxt != cur)) {
        atomicAdd(&acc[2 * cur],     ax);
        atomicAdd(&acc[2 * cur + 1], ay);
    }
}

__global__ void finalize_kernel(float2* __restrict__ out,
                                const float* __restrict__ rhoi,
                                int N)
{
    int n = blockIdx.x * blockDim.x + threadIdx.x;
    if (n < N) {
        float2 a  = out[n];
        float  sc = -1.0f / rhoi[n];
        out[n] = make_float2(a.x * sc, a.y * sc);
    }
}

extern "C" void kernel_launch(void* const* d_in, const int* in_sizes, int n_in,
                              void* d_out, int out_size, void* d_ws, size_t ws_size,
                              hipStream_t stream)
{
    // 0:i 1:j 2:ri 3:rj 4:Vi 5:Vj 6:distances 7:radialDistances
    // 8:support 9:numParticles 10:eps 11:rhoi 12:rhoj 13:pi 14:pj
    const int*   ei      = (const int*)  d_in[0];
    const int*   ej      = (const int*)  d_in[1];
    const float* Vj      = (const float*)d_in[5];
    const float* dirs    = (const float*)d_in[6];
    const float* qarr    = (const float*)d_in[7];
    const float* support = (const float*)d_in[8];
    const float* rhoi    = (const float*)d_in[11];
    const float* p_i     = (const float*)d_in[13];
    const float* p_j     = (const float*)d_in[14];

    const long long E = in_sizes[0];
    const int       N = in_sizes[11];

    float* out = (float*)d_out;
    hipMemsetAsync(out, 0, (size_t)N * 2 * sizeof(float), stream);

    const int block = 256;
    const bool packed = (ws_size >= (size_t)N * sizeof(float2));
    float2* pv = (float2*)d_ws;

    if (packed) {
        pack_pv<<<(N + block - 1) / block, block, 0, stream>>>(p_j, Vj, pv, N);
    }

    const long long nthreads = (E + CHUNK - 1) / CHUNK;
    const int grid = (int)((nthreads + block - 1) / block);
    if (packed) {
        edge_kernel<true ><<<grid, block, 0, stream>>>(ei, ej, Vj, dirs, qarr, support,
                                                       p_i, p_j, pv, out, E);
    } else {
        edge_kernel<false><<<grid, block, 0, stream>>>(ei, ej, Vj, dirs, qarr, support,
                                                       p_i, p_j, pv, out, E);
    }

    finalize_kernel<<<(N + block - 1) / block, block, 0, stream>>>((float2*)out, rhoi, N);
}